// Round 14
// baseline (256.009 us; speedup 1.0000x reference)
//
#include <hip/hip_runtime.h>
#include <hip/hip_fp16.h>
#include <math.h>

#define NN 50000
#define NE 800000
#define NB 196            // dst buckets of 256 nodes: bucket = dst >> 8
#define CPAD 16           // pad global atomic counters to one per 64B line
#define STILE 4096        // edges per stage block
#define BCAP 8192         // staged slots per bucket

typedef _Float16 v8h __attribute__((ext_vector_type(8)));
typedef float v4f __attribute__((ext_vector_type(4)));

// ---------------- convert: W0/W1/W2 -> fp16 transposed [n][k]; also zeros bhist ----------------
__global__ __launch_bounds__(256) void convert_kernel(
    const float* __restrict__ W0, const float* __restrict__ W1,
    const float* __restrict__ W2, __half* __restrict__ W0T,
    __half* __restrict__ W1T, __half* __restrict__ W2T,
    int* __restrict__ bhist) {
  int gid = blockIdx.x * 256 + threadIdx.x;
  if (gid < NB * CPAD) bhist[gid] = 0;
  if (gid < 16384) {
    int n = gid >> 7, k = gid & 127;
    W0T[gid] = __float2half(W0[k * 128 + n]);
  } else if (gid < 32768) {
    int g = gid - 16384; int n = g >> 7, k = g & 127;
    W1T[g] = __float2half(W1[k * 128 + n]);
  } else if (gid < 40960) {
    int g = gid - 32768; int n = g >> 7, k = g & 127;   // n<64, k<128
    W2T[g] = __float2half(W2[k * 64 + n]);
  }
}

// ---------------- MFMA GEMM: Y[64 x OUT] per block = X[64 x 128] @ W[128 x OUT] ----------------
template <int OUT, bool F32IN>
__global__ __launch_bounds__(256) void gemm_mfma(
    const void* __restrict__ Xv, const __half* __restrict__ WT,
    __half* __restrict__ Y, int nrows) {
  constexpr int NT = OUT / 16;
  __shared__ __align__(16) __half Xs[64][136];
  __shared__ __align__(16) __half Ws[OUT][136];
  const int tid = threadIdx.x;
  const int row0 = blockIdx.x * 64;
#pragma unroll
  for (int i = 0; i < 4; i++) {
    int ci = tid + 256 * i;
    int r = ci >> 4, ch = ci & 15;
    int g = row0 + r;
    if (F32IN) {
      const float* X32 = (const float*)Xv;
      float4 a0 = make_float4(0.f, 0.f, 0.f, 0.f), a1 = a0;
      if (g < nrows) {
        a0 = *(const float4*)&X32[(size_t)g * 128 + ch * 8];
        a1 = *(const float4*)&X32[(size_t)g * 128 + ch * 8 + 4];
      }
      union { __half2 h2[4]; int4 i4; } u;
      u.h2[0] = __floats2half2_rn(a0.x, a0.y);
      u.h2[1] = __floats2half2_rn(a0.z, a0.w);
      u.h2[2] = __floats2half2_rn(a1.x, a1.y);
      u.h2[3] = __floats2half2_rn(a1.z, a1.w);
      *(int4*)&Xs[r][ch * 8] = u.i4;
    } else {
      const __half* X16 = (const __half*)Xv;
      int4 v = make_int4(0, 0, 0, 0);
      if (g < nrows) v = *(const int4*)&X16[(size_t)g * 128 + ch * 8];
      *(int4*)&Xs[r][ch * 8] = v;
    }
  }
#pragma unroll
  for (int i = 0; i < NT; i++) {
    int ci = tid + 256 * i;
    int n = ci >> 4, ch = ci & 15;
    *(int4*)&Ws[n][ch * 8] = *(const int4*)&WT[(size_t)n * 128 + ch * 8];
  }
  __syncthreads();
  const int lane = tid & 63;
  const int w = tid >> 6;
  const int c16 = lane & 15, q = lane >> 4;
  v8h a[4];
#pragma unroll
  for (int kt = 0; kt < 4; kt++)
    a[kt] = *(const v8h*)&Xs[w * 16 + c16][kt * 32 + q * 8];
  v4f acc[NT];
#pragma unroll
  for (int t = 0; t < NT; t++) acc[t] = (v4f){0.f, 0.f, 0.f, 0.f};
#pragma unroll
  for (int t = 0; t < NT; t++) {
#pragma unroll
    for (int kt = 0; kt < 4; kt++) {
      v8h bfr = *(const v8h*)&Ws[t * 16 + c16][kt * 32 + q * 8];
      acc[t] = __builtin_amdgcn_mfma_f32_16x16x32_f16(a[kt], bfr, acc[t], 0, 0, 0);
    }
  }
#pragma unroll
  for (int t = 0; t < NT; t++)
#pragma unroll
    for (int r = 0; r < 4; r++)
      Xs[w * 16 + q * 4 + r][t * 16 + c16] = __float2half(acc[t][r]);
  __syncthreads();
  constexpr int OCH = OUT / 8;
#pragma unroll
  for (int i = 0; i < 64 * OCH / 256; i++) {
    int ci = tid + 256 * i;
    int r = ci / OCH, ch = ci % OCH;
    int g = row0 + r;
    if (g < nrows) *(int4*)&Y[(size_t)g * OUT + ch * 8] = *(const int4*)&Xs[r][ch * 8];
  }
}

// ---------------- mean aggregation (+bias, +optional LN+ReLU) -----------
// 32B/lane (two dwordx4) + packed fp16 accumulation: F=128 -> LPR=8, 8 edges in flight;
// F=64 -> LPR=4, 16 edges in flight. Per 64-edge chunk this is strictly fewer VALU ops
// than the 16B/lane variant (half the shfl broadcasts) with 2x bytes in flight per load.
template <int F, bool LN, bool HOUT>
__global__ __launch_bounds__(256) void agg_kernel(
    const __half* __restrict__ ft,
    const int* __restrict__ row_ptr, const unsigned short* __restrict__ es,
    const float* __restrict__ bias, const float* __restrict__ g,
    const float* __restrict__ beta, void* __restrict__ out_v, int n) {
  int gw = (blockIdx.x * blockDim.x + threadIdx.x) >> 6;
  int lane = threadIdx.x & 63;
  if (gw >= n) return;
  int b = row_ptr[gw], e = row_ptr[gw + 1];
  int deg = e - b;

  constexpr int LPR = F / 16;     // lanes per row (16 halves = 32B each)
  constexpr int EW  = 64 / LPR;   // edges in flight
  const int sub = lane / LPR;
  const int ll  = lane % LPR;
  __half2 hacc[8];
#pragma unroll
  for (int q = 0; q < 8; q++) hacc[q] = __floats2half2_rn(0.f, 0.f);

  for (int cb = b; cb < e; cb += 64) {
    int rem = e - cb; if (rem > 64) rem = 64;
    int sn_l = 0;
    if (lane < rem) sn_l = es[cb + lane];
    if (rem == 64) {
#pragma unroll
      for (int j = 0; j < 64; j += EW) {
        int sn = __shfl(sn_l, j + sub, 64);
        union { float4 f4; __half2 h2[4]; } u0, u1;
        u0.f4 = *(const float4*)&ft[(size_t)sn * F + ll * 16];
        u1.f4 = *(const float4*)&ft[(size_t)sn * F + ll * 16 + 8];
#pragma unroll
        for (int q = 0; q < 4; q++) {
          hacc[q] = __hadd2(hacc[q], u0.h2[q]);
          hacc[4 + q] = __hadd2(hacc[4 + q], u1.h2[q]);
        }
      }
    } else {
      for (int j = 0; j < rem; j += EW) {
        int jj = j + sub;
        int sn = __shfl(sn_l, jj, 64);
        if (jj < rem) {
          union { float4 f4; __half2 h2[4]; } u0, u1;
          u0.f4 = *(const float4*)&ft[(size_t)sn * F + ll * 16];
          u1.f4 = *(const float4*)&ft[(size_t)sn * F + ll * 16 + 8];
#pragma unroll
          for (int q = 0; q < 4; q++) {
            hacc[q] = __hadd2(hacc[q], u0.h2[q]);
            hacc[4 + q] = __hadd2(hacc[4 + q], u1.h2[q]);
          }
        }
      }
    }
  }

  // combine the EW edge streams (packed shfl over 'sub' lane bits)
#pragma unroll
  for (int o = 32; o >= LPR; o >>= 1) {
#pragma unroll
    for (int q = 0; q < 8; q++) {
      union { __half2 h; int i; } a, s;
      a.h = hacc[q];
      s.i = __shfl_xor(a.i, o, 64);
      hacc[q] = __hadd2(a.h, s.h);
    }
  }

  float acc[16];
#pragma unroll
  for (int q = 0; q < 8; q++) {
    float2 f = __half22float2(hacc[q]);
    acc[2 * q + 0] = f.x;
    acc[2 * q + 1] = f.y;
  }

  float sc = (deg > 0) ? (1.0f / (float)deg) : 0.f;
#pragma unroll
  for (int h = 0; h < 4; h++) {
    float4 b4 = *(const float4*)&bias[ll * 16 + h * 4];
    acc[4 * h + 0] = fmaf(acc[4 * h + 0], sc, b4.x);
    acc[4 * h + 1] = fmaf(acc[4 * h + 1], sc, b4.y);
    acc[4 * h + 2] = fmaf(acc[4 * h + 2], sc, b4.z);
    acc[4 * h + 3] = fmaf(acc[4 * h + 3], sc, b4.w);
  }

  if (LN) {
    float sum = 0.f;
#pragma unroll
    for (int q = 0; q < 16; q++) sum += acc[q];
#pragma unroll
    for (int o = LPR / 2; o > 0; o >>= 1) sum += __shfl_xor(sum, o, 64);
    float mean = sum * (1.0f / 128.0f);
    float var = 0.f;
#pragma unroll
    for (int q = 0; q < 16; q++) { acc[q] -= mean; var = fmaf(acc[q], acc[q], var); }
#pragma unroll
    for (int o = LPR / 2; o > 0; o >>= 1) var += __shfl_xor(var, o, 64);
    float r = rsqrtf(var * (1.0f / 128.0f) + 1e-5f);
#pragma unroll
    for (int h = 0; h < 4; h++) {
      float4 g4 = *(const float4*)&g[ll * 16 + h * 4];
      float4 be4 = *(const float4*)&beta[ll * 16 + h * 4];
      acc[4 * h + 0] = fmaxf(acc[4 * h + 0] * r * g4.x + be4.x, 0.f);
      acc[4 * h + 1] = fmaxf(acc[4 * h + 1] * r * g4.y + be4.y, 0.f);
      acc[4 * h + 2] = fmaxf(acc[4 * h + 2] * r * g4.z + be4.z, 0.f);
      acc[4 * h + 3] = fmaxf(acc[4 * h + 3] * r * g4.w + be4.w, 0.f);
    }
  }
  if (sub == 0) {
    if (HOUT) {
      __half* outh = (__half*)out_v;
      union { __half2 h2[4]; int4 i4; } v0, v1;
      v0.h2[0] = __floats2half2_rn(acc[0], acc[1]);
      v0.h2[1] = __floats2half2_rn(acc[2], acc[3]);
      v0.h2[2] = __floats2half2_rn(acc[4], acc[5]);
      v0.h2[3] = __floats2half2_rn(acc[6], acc[7]);
      v1.h2[0] = __floats2half2_rn(acc[8], acc[9]);
      v1.h2[1] = __floats2half2_rn(acc[10], acc[11]);
      v1.h2[2] = __floats2half2_rn(acc[12], acc[13]);
      v1.h2[3] = __floats2half2_rn(acc[14], acc[15]);
      *(int4*)&outh[(size_t)gw * F + ll * 16 + 0] = v0.i4;
      *(int4*)&outh[(size_t)gw * F + ll * 16 + 8] = v1.i4;
    } else {
      float* outf = (float*)out_v;
#pragma unroll
      for (int h = 0; h < 4; h++)
        *(float4*)&outf[(size_t)gw * F + ll * 16 + h * 4] =
            make_float4(acc[4 * h + 0], acc[4 * h + 1], acc[4 * h + 2], acc[4 * h + 3]);
    }
  }
}

// ---------------- CSR build v4: 2 kernels (proven R13) ----------------
__global__ __launch_bounds__(256) void stage_kernel(const int* __restrict__ src,
                                                    const int* __restrict__ dst,
                                                    int* __restrict__ bhist,
                                                    int* __restrict__ staged) {
  __shared__ int cnt[256];
  __shared__ int basep[256];
  __shared__ int cur[256];
  int tid = threadIdx.x;
  cnt[tid] = 0;
  cur[tid] = 0;
  __syncthreads();
#pragma unroll
  for (int q = 0; q < 4; q++) {
    int base = blockIdx.x * STILE + q * 1024 + tid * 4;
    if (base + 3 < NE) {
      int4 d = *(const int4*)&dst[base];
      atomicAdd(&cnt[d.x >> 8], 1);
      atomicAdd(&cnt[d.y >> 8], 1);
      atomicAdd(&cnt[d.z >> 8], 1);
      atomicAdd(&cnt[d.w >> 8], 1);
    } else {
#pragma unroll
      for (int k = 0; k < 4; k++)
        if (base + k < NE) atomicAdd(&cnt[dst[base + k] >> 8], 1);
    }
  }
  __syncthreads();
  if (tid < NB) basep[tid] = (cnt[tid] > 0) ? atomicAdd(&bhist[tid * CPAD], cnt[tid]) : 0;
  __syncthreads();
#pragma unroll
  for (int q = 0; q < 4; q++) {
    int base = blockIdx.x * STILE + q * 1024 + tid * 4;
    if (base + 3 < NE) {
      int4 d = *(const int4*)&dst[base];
      int4 s = *(const int4*)&src[base];
      int b0 = d.x >> 8, b1 = d.y >> 8, b2 = d.z >> 8, b3 = d.w >> 8;
      int p0 = atomicAdd(&cur[b0], 1);
      staged[b0 * BCAP + basep[b0] + p0] = s.x | ((d.x & 255) << 16);
      int p1 = atomicAdd(&cur[b1], 1);
      staged[b1 * BCAP + basep[b1] + p1] = s.y | ((d.y & 255) << 16);
      int p2 = atomicAdd(&cur[b2], 1);
      staged[b2 * BCAP + basep[b2] + p2] = s.z | ((d.z & 255) << 16);
      int p3 = atomicAdd(&cur[b3], 1);
      staged[b3 * BCAP + basep[b3] + p3] = s.w | ((d.w & 255) << 16);
    } else {
#pragma unroll
      for (int k = 0; k < 4; k++) {
        if (base + k < NE) {
          int d = dst[base + k], s = src[base + k];
          int bb = d >> 8;
          int pp = atomicAdd(&cur[bb], 1);
          staged[bb * BCAP + basep[bb] + pp] = s | ((d & 255) << 16);
        }
      }
    }
  }
}

__global__ __launch_bounds__(256) void bucket_csr_kernel(const int* __restrict__ staged,
                                                         const int* __restrict__ bhist,
                                                         int* __restrict__ row_ptr,
                                                         unsigned short* __restrict__ es) {
  int b = blockIdx.x;
  int tid = threadIdx.x;
  int lane = tid & 63, wid = tid >> 6;
  __shared__ int sbase[256];
  __shared__ int wsum[4];
  __shared__ int cnt[256];
  __shared__ int fill_l[256];
  int tv = (tid < NB) ? bhist[tid * CPAD] : 0;
  int x = tv;
#pragma unroll
  for (int o = 1; o < 64; o <<= 1) {
    int y = __shfl_up(x, o, 64);
    if (lane >= o) x += y;
  }
  if (lane == 63) wsum[wid] = x;
  __syncthreads();
  int wpre = 0;
  for (int w = 0; w < wid; w++) wpre += wsum[w];
  sbase[tid] = wpre + x - tv;
  cnt[tid] = 0;
  __syncthreads();
  int lo = sbase[b];
  int cntb = bhist[b * CPAD];
  const int* st = &staged[b * BCAP];
  for (int i = tid; i < cntb; i += 256)
    atomicAdd(&cnt[(st[i] >> 16) & 255], 1);
  __syncthreads();
  int v = cnt[tid];
  x = v;
#pragma unroll
  for (int o = 1; o < 64; o <<= 1) {
    int y = __shfl_up(x, o, 64);
    if (lane >= o) x += y;
  }
  __syncthreads();
  if (lane == 63) wsum[wid] = x;
  __syncthreads();
  wpre = 0;
  for (int w = 0; w < wid; w++) wpre += wsum[w];
  int start = lo + wpre + x - v;
  int node = (b << 8) + tid;
  if (node < NN) row_ptr[node] = start;
  fill_l[tid] = start;
  __syncthreads();
  for (int i = tid; i < cntb; i += 256) {
    int w = st[i];
    int pos = atomicAdd(&fill_l[(w >> 16) & 255], 1);
    es[pos] = (unsigned short)(w & 0xFFFF);
  }
  if (b == 0 && tid == 0) row_ptr[NN] = NE;
}

// ---------------- orchestration ----------------
extern "C" void kernel_launch(void* const* d_in, const int* in_sizes, int n_in,
                              void* d_out, int out_size, void* d_ws, size_t ws_size,
                              hipStream_t stream) {
  (void)in_sizes; (void)n_in; (void)out_size; (void)ws_size;
  const float* feat = (const float*)d_in[0];
  const int* src = (const int*)d_in[1];
  const int* dst = (const int*)d_in[2];
  const float* W0 = (const float*)d_in[3];
  const float* b0 = (const float*)d_in[4];
  const float* W1 = (const float*)d_in[5];
  const float* b1 = (const float*)d_in[6];
  const float* W2 = (const float*)d_in[7];
  const float* b2 = (const float*)d_in[8];
  const float* ln1g = (const float*)d_in[9];
  const float* ln1b = (const float*)d_in[10];
  const float* ln2g = (const float*)d_in[11];
  const float* ln2b = (const float*)d_in[12];
  float* out = (float*)d_out;

  char* p = (char*)d_ws;
  auto alloc = [&](size_t bytes) {
    char* r = p;
    p += (bytes + 255) & ~size_t(255);
    return r;
  };
  __half* fth      = (__half*)alloc((size_t)NN * 128 * 2);
  __half* hh       = (__half*)alloc((size_t)NN * 128 * 2);
  __half* W0T      = (__half*)alloc(128 * 128 * 2);
  __half* W1T      = (__half*)alloc(128 * 128 * 2);
  __half* W2T      = (__half*)alloc(64 * 128 * 2);
  int* row_ptr     = (int*)alloc((size_t)(NN + 1) * 4);
  unsigned short* es = (unsigned short*)alloc((size_t)NE * 2);
  int* staged      = (int*)alloc((size_t)NB * BCAP * 4);
  int* bhist       = (int*)alloc((size_t)NB * CPAD * 4);

  // convert weights + zero bhist
  convert_kernel<<<160, 256, 0, stream>>>(W0, W1, W2, W0T, W1T, W2T, bhist);

  // CSR by dst (graph identical for all 3 convs): 2 kernels
  int sb = (NE + STILE - 1) / STILE;   // 196 blocks
  stage_kernel<<<sb, 256, 0, stream>>>(src, dst, bhist, staged);
  bucket_csr_kernel<<<NB, 256, 0, stream>>>(staged, bhist, row_ptr, es);

  int gb = (NN + 63) / 64;     // 782
  int nwb = (NN + 3) / 4;

  gemm_mfma<128, true><<<gb, 256, 0, stream>>>(feat, W0T, fth, NN);
  agg_kernel<128, true, true><<<nwb, 256, 0, stream>>>(fth, row_ptr, es, b0, ln1g, ln1b, hh, NN);
  gemm_mfma<128, false><<<gb, 256, 0, stream>>>(hh, W1T, fth, NN);
  agg_kernel<128, true, true><<<nwb, 256, 0, stream>>>(fth, row_ptr, es, b1, ln2g, ln2b, hh, NN);
  gemm_mfma<64, false><<<gb, 256, 0, stream>>>(hh, W2T, fth, NN);
  agg_kernel<64, false, false><<<nwb, 256, 0, stream>>>(fth, row_ptr, es, b2, nullptr, nullptr, out, NN);
}